// Round 12
// baseline (48.161 us; speedup 1.0000x reference)
//
#include <hip/hip_runtime.h>

// TransMatch scalarized (validated absmax=0 since R2):
//   score = b + Rw[r0] + sum_p( EW[e_p] + i_p*rw0_p + 0.25*i_p*S_p )
//   S_p = sum_n m0 * (EW[node_n] + rwsum_n / max(cnt_n,1))
// R12: remove the dominant gather term. 74% of main's L2-line touches were
// the 1024 random rel-table probes per block. But per-entity
//   RS[n] = sum_{s<16} Rw[rel[entity2edges[n][s]]]
// is batch-invariant; the te-mask only subtracts matches:
//   rwsum_n = RS[node] - matches_n * Rw[rel[te]],  cnt_n = 16 - matches_n
// (matches_n counted from the edge-id rows main already reads for masking).
// K1 precomputes RS[200K] (12.8MB coalesced + 3.2M rel gathers aliasing onto
// the 8MB e2r table). Main: ~420 lines/block instead of ~1375. No nib table.

#define DIM 64
#define NS 16
#define NREL 16

// ---------------- K1: RS[n] = sum_s Rw[rel[e2e[n][s]]] ----------------
__global__ __launch_bounds__(256) void rs_precompute(
    const int* __restrict__ entity2edges,   // (N_ENT,16)
    const int* __restrict__ e2r,            // (N_EDGE,)
    const float* __restrict__ relation_emb, // (16,64)
    const float* __restrict__ scorer_w,     // (64,)
    float* __restrict__ RS,                 // (N_ENT,)
    int n_ent)
{
    __shared__ float RwL[NREL];
    const int t = threadIdx.x;

    if (t < 64) {
        const int r = t >> 2, seg = t & 3;
        const float4* R4 = reinterpret_cast<const float4*>(relation_emb);
        const float4* W4 = reinterpret_cast<const float4*>(scorer_w);
        float v = 0.0f;
        #pragma unroll
        for (int k = 0; k < 4; ++k) {
            const float4 rr = R4[r * 16 + seg * 4 + k];
            const float4 ww = W4[seg * 4 + k];
            v = fmaf(rr.x, ww.x, v); v = fmaf(rr.y, ww.y, v);
            v = fmaf(rr.z, ww.z, v); v = fmaf(rr.w, ww.w, v);
        }
        v += __shfl_xor(v, 1); v += __shfl_xor(v, 2);
        if (seg == 0) RwL[r] = v;
    }
    __syncthreads();

    const int n = blockIdx.x * 256 + t;
    if (n < n_ent) {
        const int4* row = reinterpret_cast<const int4*>(entity2edges + (size_t)n * NS);
        const int4 a = row[0], b = row[1], c = row[2], d = row[3];
        // 16 independent rel gathers (alias onto 8MB table -> cache-resident)
        float rs = 0.0f;
        rs += RwL[e2r[a.x] & 15]; rs += RwL[e2r[a.y] & 15];
        rs += RwL[e2r[a.z] & 15]; rs += RwL[e2r[a.w] & 15];
        rs += RwL[e2r[b.x] & 15]; rs += RwL[e2r[b.y] & 15];
        rs += RwL[e2r[b.z] & 15]; rs += RwL[e2r[b.w] & 15];
        rs += RwL[e2r[c.x] & 15]; rs += RwL[e2r[c.y] & 15];
        rs += RwL[e2r[c.z] & 15]; rs += RwL[e2r[c.w] & 15];
        rs += RwL[e2r[d.x] & 15]; rs += RwL[e2r[d.y] & 15];
        rs += RwL[e2r[d.z] & 15]; rs += RwL[e2r[d.w] & 15];
        RS[n] = rs;
    }
}

// ---------------- K2: main ----------------
__global__ __launch_bounds__(512, 8) void transmatch_main(
    const int* __restrict__ relations,       // (BS,)
    const int* __restrict__ entity_pairs,    // (BS,2)
    const int* __restrict__ train_edges,     // (BS,)
    const int* __restrict__ entity2edges,    // (N_ENT,16)
    const int* __restrict__ edge2entities,   // (N_EDGE,2)
    const int* __restrict__ e2r,             // (N_EDGE,)
    const float* __restrict__ relation_emb,  // (16,64)
    const float* __restrict__ entity_emb,    // (N_ENT,64)
    const float* __restrict__ scorer_w,      // (64,)
    const float* __restrict__ scorer_b,      // (1,)
    const float* __restrict__ RS,            // (N_ENT,)
    float* __restrict__ out)                 // (BS,)
{
    __shared__ float RwL[NREL];
    __shared__ float wL[DIM];
    __shared__ int   node_l[64];
    __shared__ int   m0i[32];
    __shared__ float c0s[2];
    __shared__ float ews[2];
    __shared__ float rsp[2];      // RS[e_p]
    __shared__ int   srte;        // rel[te]
    __shared__ float wavesum[8];

    const int b    = blockIdx.x;
    const int t    = threadIdx.x;
    const int lane = t & 63;
    const int wave = t >> 6;
    const int te   = train_edges[b];

    if (t < DIM) wL[t] = scorer_w[t];

    if (wave == 0 && lane < 32) {
        // first hop: j = p*16 + s; mask + node discovery (no rel gather)
        const int p    = lane >> 4;
        const int e    = entity_pairs[b * 2 + p];
        const int edge = entity2edges[e * NS + (lane & 15)];
        const int m0   = (edge != te) ? 1 : 0;
        const int2 nn = reinterpret_cast<const int2*>(edge2entities)[edge];
        reinterpret_cast<int2*>(node_l)[lane] = nn;
        m0i[lane] = m0;
        int c = m0;
        c += __shfl_xor(c, 1); c += __shfl_xor(c, 2);
        c += __shfl_xor(c, 4); c += __shfl_xor(c, 8);
        if ((lane & 15) == 0) c0s[p] = (float)c;
    } else if (wave == 1) {
        // EW[e_p] + RS[e_p]
        const int p  = lane >> 5;
        const int e  = entity_pairs[b * 2 + p];
        const int k  = lane & 31;
        const float2 ev = reinterpret_cast<const float2*>(entity_emb)[e * 32 + k];
        float v = ev.x * scorer_w[2 * k] + ev.y * scorer_w[2 * k + 1];
        v += __shfl_xor(v, 1); v += __shfl_xor(v, 2); v += __shfl_xor(v, 4);
        v += __shfl_xor(v, 8); v += __shfl_xor(v, 16);
        if (k == 0) { ews[p] = v; rsp[p] = RS[e]; }
    } else if (wave == 2) {
        // Rw[r] = dot(R[r], w)
        const int r = lane >> 2, seg = lane & 3;
        const float4* R4 = reinterpret_cast<const float4*>(relation_emb);
        const float4* W4 = reinterpret_cast<const float4*>(scorer_w);
        float v = 0.0f;
        #pragma unroll
        for (int k = 0; k < 4; ++k) {
            const float4 rr = R4[r * 16 + seg * 4 + k];
            const float4 ww = W4[seg * 4 + k];
            v = fmaf(rr.x, ww.x, v); v = fmaf(rr.y, ww.y, v);
            v = fmaf(rr.z, ww.z, v); v = fmaf(rr.w, ww.w, v);
        }
        v += __shfl_xor(v, 1); v += __shfl_xor(v, 2);
        if (seg == 0) RwL[r] = v;
    } else if (wave == 3) {
        if (lane == 0) srte = e2r[te] & 15;   // rel of the train edge
    }
    __syncthreads();

    // second hop: thread t -> node n = t>>3, edge-pair h = t&7 (2 edges each)
    {
        const int n    = t >> 3;
        const int h    = t & 7;
        const int node = node_l[n];

        const int2 ed = reinterpret_cast<const int2*>(entity2edges)[node * 8 + h];
        int matches = ((ed.x == te) ? 1 : 0) + ((ed.y == te) ? 1 : 0);

        // entity row segment: dims [h*8, h*8+8)
        const float4* E4  = reinterpret_cast<const float4*>(entity_emb);
        const float4* wL4 = reinterpret_cast<const float4*>(wL);
        const float4 ev0 = E4[node * 16 + h * 2];
        const float4 ev1 = E4[node * 16 + h * 2 + 1];
        const float4 w0  = wL4[h * 2];
        const float4 w1  = wL4[h * 2 + 1];
        float dotp = 0.0f;
        dotp = fmaf(ev0.x, w0.x, dotp); dotp = fmaf(ev0.y, w0.y, dotp);
        dotp = fmaf(ev0.z, w0.z, dotp); dotp = fmaf(ev0.w, w0.w, dotp);
        dotp = fmaf(ev1.x, w1.x, dotp); dotp = fmaf(ev1.y, w1.y, dotp);
        dotp = fmaf(ev1.z, w1.z, dotp); dotp = fmaf(ev1.w, w1.w, dotp);

        dotp    += __shfl_xor(dotp, 1); dotp    += __shfl_xor(dotp, 2); dotp    += __shfl_xor(dotp, 4);
        matches += __shfl_xor(matches, 1); matches += __shfl_xor(matches, 2); matches += __shfl_xor(matches, 4);

        float v = 0.0f;
        if (h == 0 && m0i[n >> 1]) {
            const float rwte = RwL[srte];
            const float rws  = RS[node] - (float)matches * rwte;
            const int   cnt  = NS - matches;
            v = dotp + rws / (float)max(cnt, 1);
        }

        v += __shfl_xor(v, 8); v += __shfl_xor(v, 16); v += __shfl_xor(v, 32);
        if (lane == 0) wavesum[wave] = v;
    }
    __syncthreads();

    if (t == 0) {
        const float rwte = RwL[srte];
        const float i0 = 1.0f / fmaxf(c0s[0], 1.0f);
        const float i1 = 1.0f / fmaxf(c0s[1], 1.0f);
        // hop-1 masked rel sums via RS - matches*Rwte (matches = 16 - c0)
        const float rw00 = rsp[0] - (16.0f - c0s[0]) * rwte;
        const float rw01 = rsp[1] - (16.0f - c0s[1]) * rwte;
        const float S0 = wavesum[0] + wavesum[1] + wavesum[2] + wavesum[3];
        const float S1 = wavesum[4] + wavesum[5] + wavesum[6] + wavesum[7];
        const int   r0 = relations[b];
        out[b] = scorer_b[0] + RwL[r0]
               + ews[0] + i0 * rw00 + 0.25f * i0 * S0
               + ews[1] + i1 * rw01 + 0.25f * i1 * S1;
    }
}

extern "C" void kernel_launch(void* const* d_in, const int* in_sizes, int n_in,
                              void* d_out, int out_size, void* d_ws, size_t ws_size,
                              hipStream_t stream) {
    const int*   relations     = (const int*)d_in[0];
    const int*   entity_pairs  = (const int*)d_in[1];
    const int*   train_edges   = (const int*)d_in[2];
    const int*   entity2edges  = (const int*)d_in[3];
    const int*   edge2entities = (const int*)d_in[4];
    const int*   edge2relation = (const int*)d_in[5];
    const float* relation_emb  = (const float*)d_in[6];
    const float* entity_emb    = (const float*)d_in[7];
    const float* scorer_w      = (const float*)d_in[8];
    const float* scorer_b      = (const float*)d_in[9];
    float* out = (float*)d_out;

    const int bs    = in_sizes[0];
    const int n_ent = in_sizes[3] / NS;   // entity2edges is (N_ENT, 16)

    float* RS = (float*)d_ws;             // 800KB per-entity rel-sum table

    rs_precompute<<<(n_ent + 255) / 256, 256, 0, stream>>>(
        entity2edges, edge2relation, relation_emb, scorer_w, RS, n_ent);

    transmatch_main<<<bs, 512, 0, stream>>>(
        relations, entity_pairs, train_edges, entity2edges, edge2entities,
        edge2relation, relation_emb, entity_emb, scorer_w, scorer_b, RS, out);
}

// Round 13
// 20.362 us; speedup vs baseline: 2.3653x; 2.3653x over previous
//
#include <hip/hip_runtime.h>

// TransMatch scalarized (validated absmax=0 since R2):
//   score = b + Rw[r0] + sum_p( EW[e_p] + i_p*rw0sum_p
//                               + 0.25*i_p*sum_{n in p} m0_j*(EW[node_n] + rwsum_n/cnt_n) )
// R13: FINAL — revert to R6 (session best, 20.56/20.66us reproduced).
// Session ledger:
//  - R8 3x-probe: total = ~9us fixed replay overhead + ~1.5us pack + ~9.6us main
//  - R10 profile: main FETCH == intrinsic unique-line working set (no over-fetch);
//    ~2.3TB/s effective random-line service (L2-miss-path bound)
//  - R12: per-entity RS precompute = 3.2M non-resident gathers (38.7us) vs
//    R6's 1.0M L2-resident gathers -> gather-count x residency is the cost
//    function and R6 minimizes it among all structures tried.
//  - R3 (2x occupancy): +6.5% only; R5 (NT hints): regression; R7 (flatten):
//    regression; R9/R10 (cooperative fusion): 3x regression.
// Structure: pack e2r -> 1MB nibble table (L2-resident), then 1024 blk x 512
// thr main @ (512,8); per-block: 32-lane hop-1 front, 64-node hop-2 with
// 2 edges/thread, all-scalar (dot-with-w collapsed) math.

#define DIM 64
#define NS 16
#define NREL 16

__global__ __launch_bounds__(256) void pack_nib_kernel(
    const int* __restrict__ e2r, unsigned int* __restrict__ nib, int n) {
    const int tid = blockIdx.x * blockDim.x + threadIdx.x;
    const int i = tid * 8;
    if (i + 7 < n) {
        const int4 a = *reinterpret_cast<const int4*>(e2r + i);
        const int4 b = *reinterpret_cast<const int4*>(e2r + i + 4);
        nib[tid] =  (unsigned int)(a.x & 15)
                 | ((unsigned int)(a.y & 15) << 4)
                 | ((unsigned int)(a.z & 15) << 8)
                 | ((unsigned int)(a.w & 15) << 12)
                 | ((unsigned int)(b.x & 15) << 16)
                 | ((unsigned int)(b.y & 15) << 20)
                 | ((unsigned int)(b.z & 15) << 24)
                 | ((unsigned int)(b.w & 15) << 28);
    } else if (i < n) {
        unsigned int w = 0;
        for (int k = 0; k < 8 && i + k < n; ++k)
            w |= ((unsigned int)(e2r[i + k] & 15)) << (4 * k);
        nib[tid] = w;
    }
}

__device__ __forceinline__ int rel4(const unsigned int* __restrict__ nib, int e) {
    return (int)((nib[e >> 3] >> ((e & 7) << 2)) & 15u);
}

__global__ __launch_bounds__(512, 8) void transmatch_main(
    const int* __restrict__ relations,       // (BS,)
    const int* __restrict__ entity_pairs,    // (BS,2)
    const int* __restrict__ train_edges,     // (BS,)
    const int* __restrict__ entity2edges,    // (N_ENT,16)
    const int* __restrict__ edge2entities,   // (N_EDGE,2)
    const float* __restrict__ relation_emb,  // (16,64)
    const float* __restrict__ entity_emb,    // (N_ENT,64)
    const float* __restrict__ scorer_w,      // (64,)
    const float* __restrict__ scorer_b,      // (1,)
    const unsigned int* __restrict__ nib,    // (N_EDGE/8,) nibble-packed rels
    float* __restrict__ out)                 // (BS,)
{
    __shared__ float RwL[NREL];   // dot(R[r], w)
    __shared__ float wL[DIM];
    __shared__ int   node_l[64];
    __shared__ int   m0i[32];
    __shared__ float c0s[2];
    __shared__ float ews[2];
    __shared__ float rw0s[2];
    __shared__ float wavesum[8];

    const int b    = blockIdx.x;
    const int t    = threadIdx.x;
    const int lane = t & 63;
    const int wave = t >> 6;
    const int te   = train_edges[b];

    if (t < DIM) wL[t] = scorer_w[t];

    int rel1 = 0, m0 = 0;  // live across the barrier in wave-0 lanes<32
    if (wave == 0 && lane < 32) {
        // first hop: j = p*16 + s
        const int p    = lane >> 4;
        const int e    = entity_pairs[b * 2 + p];
        const int edge = entity2edges[e * NS + (lane & 15)];
        m0   = (edge != te) ? 1 : 0;
        rel1 = rel4(nib, edge);
        const int2 nn = reinterpret_cast<const int2*>(edge2entities)[edge];
        reinterpret_cast<int2*>(node_l)[lane] = nn;
        m0i[lane] = m0;
        int c = m0;
        c += __shfl_xor(c, 1); c += __shfl_xor(c, 2);
        c += __shfl_xor(c, 4); c += __shfl_xor(c, 8);
        if ((lane & 15) == 0) c0s[p] = (float)c;
    } else if (wave == 1) {
        // EW[e_p] = dot(entity_emb[e_p], w)  (32 lanes per pair entity)
        const int p  = lane >> 5;
        const int e  = entity_pairs[b * 2 + p];
        const int k  = lane & 31;
        const float2 ev = reinterpret_cast<const float2*>(entity_emb)[e * 32 + k];
        float v = ev.x * scorer_w[2 * k] + ev.y * scorer_w[2 * k + 1];
        v += __shfl_xor(v, 1); v += __shfl_xor(v, 2); v += __shfl_xor(v, 4);
        v += __shfl_xor(v, 8); v += __shfl_xor(v, 16);
        if (k == 0) ews[p] = v;
    } else if (wave == 2) {
        // Rw[r] = dot(R[r], w): r = lane>>2, seg = lane&3 covers 16 dims
        const int r = lane >> 2, seg = lane & 3;
        const float4* R4 = reinterpret_cast<const float4*>(relation_emb);
        const float4* W4 = reinterpret_cast<const float4*>(scorer_w);
        float v = 0.0f;
        #pragma unroll
        for (int k = 0; k < 4; ++k) {
            const float4 rr = R4[r * 16 + seg * 4 + k];
            const float4 ww = W4[seg * 4 + k];
            v = fmaf(rr.x, ww.x, v); v = fmaf(rr.y, ww.y, v);
            v = fmaf(rr.z, ww.z, v); v = fmaf(rr.w, ww.w, v);
        }
        v += __shfl_xor(v, 1); v += __shfl_xor(v, 2);
        if (seg == 0) RwL[r] = v;
    }
    __syncthreads();

    // finish first-hop masked Rw sum (needed RwL)
    if (wave == 0 && lane < 32) {
        float rv = m0 ? RwL[rel1] : 0.0f;
        rv += __shfl_xor(rv, 1); rv += __shfl_xor(rv, 2);
        rv += __shfl_xor(rv, 4); rv += __shfl_xor(rv, 8);
        if ((lane & 15) == 0) rw0s[lane >> 4] = rv;
    }

    // second hop: thread t -> node n = t>>3, edge-pair h = t&7 (2 edges each)
    {
        const int n    = t >> 3;
        const int h    = t & 7;
        const int node = node_l[n];

        const int2 ed = reinterpret_cast<const int2*>(entity2edges)[node * 8 + h];
        const int ra = rel4(nib, ed.x);
        const int rb = rel4(nib, ed.y);

        // entity row segment: dims [h*8, h*8+8)  (8 lanes cover the 256B row)
        const float4* E4  = reinterpret_cast<const float4*>(entity_emb);
        const float4* wL4 = reinterpret_cast<const float4*>(wL);
        const float4 ev0 = E4[node * 16 + h * 2];
        const float4 ev1 = E4[node * 16 + h * 2 + 1];
        const float4 w0  = wL4[h * 2];
        const float4 w1  = wL4[h * 2 + 1];
        float dotp = 0.0f;
        dotp = fmaf(ev0.x, w0.x, dotp); dotp = fmaf(ev0.y, w0.y, dotp);
        dotp = fmaf(ev0.z, w0.z, dotp); dotp = fmaf(ev0.w, w0.w, dotp);
        dotp = fmaf(ev1.x, w1.x, dotp); dotp = fmaf(ev1.y, w1.y, dotp);
        dotp = fmaf(ev1.z, w1.z, dotp); dotp = fmaf(ev1.w, w1.w, dotp);

        int cnt = 0; float rws = 0.0f;
        if (ed.x != te) { cnt++; rws += RwL[ra]; }
        if (ed.y != te) { cnt++; rws += RwL[rb]; }

        // reduce over the node's 8 threads
        dotp += __shfl_xor(dotp, 1); dotp += __shfl_xor(dotp, 2); dotp += __shfl_xor(dotp, 4);
        rws  += __shfl_xor(rws, 1);  rws  += __shfl_xor(rws, 2);  rws  += __shfl_xor(rws, 4);
        cnt  += __shfl_xor(cnt, 1);  cnt  += __shfl_xor(cnt, 2);  cnt  += __shfl_xor(cnt, 4);

        float v = 0.0f;
        if (h == 0 && m0i[n >> 1])
            v = dotp + rws / (float)max(cnt, 1);

        // sum the wave's 8 nodes (h!=0 lanes contribute 0)
        v += __shfl_xor(v, 8); v += __shfl_xor(v, 16); v += __shfl_xor(v, 32);
        if (lane == 0) wavesum[wave] = v;
    }
    __syncthreads();

    if (t == 0) {
        const float i0 = 1.0f / fmaxf(c0s[0], 1.0f);
        const float i1 = 1.0f / fmaxf(c0s[1], 1.0f);
        // waves 0-3 cover nodes 0..31 (pair 0), waves 4-7 nodes 32..63 (pair 1)
        const float S0 = wavesum[0] + wavesum[1] + wavesum[2] + wavesum[3];
        const float S1 = wavesum[4] + wavesum[5] + wavesum[6] + wavesum[7];
        const int   r0 = relations[b];
        out[b] = scorer_b[0] + RwL[r0]
               + ews[0] + i0 * rw0s[0] + 0.25f * i0 * S0
               + ews[1] + i1 * rw0s[1] + 0.25f * i1 * S1;
    }
}

extern "C" void kernel_launch(void* const* d_in, const int* in_sizes, int n_in,
                              void* d_out, int out_size, void* d_ws, size_t ws_size,
                              hipStream_t stream) {
    const int*   relations     = (const int*)d_in[0];
    const int*   entity_pairs  = (const int*)d_in[1];
    const int*   train_edges   = (const int*)d_in[2];
    const int*   entity2edges  = (const int*)d_in[3];
    const int*   edge2entities = (const int*)d_in[4];
    const int*   edge2relation = (const int*)d_in[5];
    const float* relation_emb  = (const float*)d_in[6];
    const float* entity_emb    = (const float*)d_in[7];
    const float* scorer_w      = (const float*)d_in[8];
    const float* scorer_b      = (const float*)d_in[9];
    float* out = (float*)d_out;

    const int bs     = in_sizes[0];
    const int n_edge = in_sizes[5];
    const int n_words = (n_edge + 7) / 8;

    unsigned int* nib = (unsigned int*)d_ws;  // 1MB nibble-packed rel table
    pack_nib_kernel<<<(n_words + 255) / 256, 256, 0, stream>>>(
        edge2relation, nib, n_edge);

    transmatch_main<<<bs, 512, 0, stream>>>(
        relations, entity_pairs, train_edges, entity2edges, edge2entities,
        relation_emb, entity_emb, scorer_w, scorer_b, nib, out);
}